// Round 5
// baseline (12597.682 us; speedup 1.0000x reference)
//
#include <hip/hip_runtime.h>
#include <hip/hip_bf16.h>
#include <hip/hip_fp16.h>

// Problem constants
constexpr int nB = 64, nT = 2048, nIN = 32, nH = 256, nS = 256, nOUT = 32, nNB = 4;
constexpr int nBT = nB * nT;  // 131072

typedef __attribute__((ext_vector_type(2))) _Float16 half2v;
typedef __attribute__((ext_vector_type(4))) float f32x4;
typedef __attribute__((ext_vector_type(8))) short bf16x8;
typedef __attribute__((ext_vector_type(4))) unsigned short us4;
typedef __attribute__((ext_vector_type(4))) unsigned int uint4v;

#define GLDS(gsrc, ldst)                                                        \
  __builtin_amdgcn_global_load_lds(                                             \
      (const __attribute__((address_space(1))) void*)(gsrc),                    \
      (__attribute__((address_space(3))) void*)(ldst), 16, 0, 0)

__device__ __forceinline__ float fast_exp(float x) {
  return __builtin_amdgcn_exp2f(x * 1.44269504088896f);
}
__device__ __forceinline__ float sigm(float x) {
  return __builtin_amdgcn_rcpf(1.f + fast_exp(-x));
}
__device__ __forceinline__ float tanh_f(float x) {
  float ax = fabsf(x);
  float e = fast_exp(-2.f * ax);
  float r = 1.f - 2.f * e * __builtin_amdgcn_rcpf(1.f + e);
  return copysignf(r, x);
}
__device__ __forceinline__ float gelu_f(float x) {
  float x3 = x * x * x;
  return 0.5f * x * (1.f + tanh_f(0.79788456080286536f * (x + 0.044715f * x3)));
}
__device__ __forceinline__ unsigned short f2bf(float f) {
  unsigned int u = __builtin_bit_cast(unsigned int, f);
  unsigned int r = (u + 0x7fffu + ((u >> 16) & 1u)) >> 16;
  return (unsigned short)r;
}
__device__ __forceinline__ float fdot2_(half2v a, half2v b, float c) {
#if __has_builtin(__builtin_amdgcn_fdot2)
  return __builtin_amdgcn_fdot2(a, b, c, false);
#else
  return fmaf((float)a.x, (float)b.x, fmaf((float)a.y, (float)b.y, c));
#endif
}

// ---------------- weight prep ----------------
__global__ __launch_bounds__(256) void k_cvt_bf16(const float* __restrict__ src,
                                                  unsigned short* __restrict__ dst, int n) {
  for (int i = blockIdx.x * 256 + threadIdx.x; i < n; i += gridDim.x * 256)
    dst[i] = f2bf(src[i]);
}

// whh (NB,768,256) f32 -> per-thread packed half2 for the 1024-thread scan:
// layout idx = ((i*1024 + t)*3 + g)*32 + kk ; t=(j<<2)|p ; k0 = p*64 + 2*kk
__global__ __launch_bounds__(256) void k_pack_whh(const float* __restrict__ whh,
                                                  unsigned int* __restrict__ dst) {
  int idx = blockIdx.x * 256 + threadIdx.x;
  int total = nNB * 1024 * 3 * 32;
  if (idx >= total) return;
  int kk = idx & 31;
  int rest = idx >> 5;
  int g = rest % 3;
  int rest2 = rest / 3;
  int t = rest2 & 1023;
  int i = rest2 >> 10;
  int j = t >> 2, p = t & 3;
  int k0 = p * 64 + kk * 2;
  const float* wrow = whh + ((size_t)i * 768 + g * 256 + j) * 256;
  unsigned short a = __builtin_bit_cast(unsigned short, (_Float16)wrow[k0]);
  unsigned short b = __builtin_bit_cast(unsigned short, (_Float16)wrow[k0 + 1]);
  dst[idx] = (unsigned int)a | ((unsigned int)b << 16);
}

// ---------------- encoder ----------------
__global__ __launch_bounds__(256) void k_encoder(const float* __restrict__ x,
                                                 const float* __restrict__ ew,
                                                 const float* __restrict__ eb,
                                                 float* __restrict__ h) {
  __shared__ float xs[32][32];
  int tid = threadIdx.x;
  int r0 = blockIdx.x * 32;
  for (int q = tid; q < 32 * 32; q += 256)
    xs[q >> 5][q & 31] = x[(size_t)(r0 + (q >> 5)) * nIN + (q & 31)];
  float w[32];
#pragma unroll
  for (int k = 0; k < 32; k++) w[k] = ew[tid * 32 + k];
  float b = eb[tid];
  __syncthreads();
  for (int r = 0; r < 32; r++) {
    float acc = b;
#pragma unroll
    for (int k = 0; k < 32; k++) acc = fmaf(xs[r][k], w[k], acc);
    h[(size_t)(r0 + r) * nH + tid] = acc;
  }
}

// ---------------- batchnorm stats ----------------
__global__ __launch_bounds__(256) void k_bn_partial(const float* __restrict__ h,
                                                    float* __restrict__ psum,
                                                    float* __restrict__ psq) {
  int c = threadIdx.x;
  int blk = blockIdx.x;  // 1024 blocks x 128 rows
  size_t base = (size_t)blk * 128 * nH + c;
  float s = 0.f, s2 = 0.f;
  for (int r = 0; r < 128; r++) {
    float v = h[base + (size_t)r * nH];
    s += v;
    s2 = fmaf(v, v, s2);
  }
  psum[c * 1024 + blk] = s;
  psq[c * 1024 + blk] = s2;
}

__global__ __launch_bounds__(256) void k_bn_final(const float* __restrict__ psum,
                                                  const float* __restrict__ psq,
                                                  float* __restrict__ mean,
                                                  float* __restrict__ istd) {
  int c = blockIdx.x;
  int t = threadIdx.x;
  __shared__ float rs[256], rq[256];
  float s = 0.f, q = 0.f;
#pragma unroll
  for (int p = 0; p < 4; p++) {
    s += psum[c * 1024 + t + 256 * p];
    q += psq[c * 1024 + t + 256 * p];
  }
  rs[t] = s;
  rq[t] = q;
  __syncthreads();
  for (int off = 128; off; off >>= 1) {
    if (t < off) {
      rs[t] += rs[t + off];
      rq[t] += rq[t + off];
    }
    __syncthreads();
  }
  if (t == 0) {
    float m = rs[0] * (1.f / (float)nBT);
    float v = rq[0] * (1.f / (float)nBT) - m * m;
    mean[c] = m;
    istd[c] = rsqrtf(v + 1e-5f);
  }
}

__global__ __launch_bounds__(256) void k_norm_cvt(const float* __restrict__ h,
                                                  const float* __restrict__ mean,
                                                  const float* __restrict__ istd,
                                                  unsigned short* __restrict__ hn) {
  __shared__ float ms[256], is[256];
  int t = threadIdx.x;
  ms[t] = mean[t];
  is[t] = istd[t];
  __syncthreads();
  size_t total = (size_t)nBT * (nH / 4);
  for (size_t idx = (size_t)blockIdx.x * 256 + t; idx < total; idx += (size_t)gridDim.x * 256) {
    f32x4 v = ((const f32x4*)h)[idx];
    int c0 = (int)((idx & 63) * 4);
    us4 o;
    o.x = f2bf((v.x - ms[c0 + 0]) * is[c0 + 0]);
    o.y = f2bf((v.y - ms[c0 + 1]) * is[c0 + 1]);
    o.z = f2bf((v.z - ms[c0 + 2]) * is[c0 + 2]);
    o.w = f2bf((v.w - ms[c0 + 3]) * is[c0 + 3]);
    ((us4*)hn)[idx] = o;
  }
}

// ---------------- GEMM: ig_chunk = hn_chunk @ wih^T + b_ih --------------------------
__global__ __launch_bounds__(256) void k_gemm_ig(const unsigned short* __restrict__ A,
                                                 const unsigned short* __restrict__ W,
                                                 const float* __restrict__ bih,
                                                 _Float16* __restrict__ out,
                                                 int t0, int tcShift) {
  __shared__ __align__(16) unsigned short As[128 * 32];
  __shared__ __align__(16) unsigned short Bs[128 * 32];
  const int tid = threadIdx.x;
  const int lane = tid & 63, wid = tid >> 6;
  const int m0 = blockIdx.y * 128, n0 = blockIdx.x * 128;
  const int wrow = wid >> 1, wcol = wid & 1;
  const int srow = tid >> 2;
  const int scol = (tid & 3) * 8;
  const int bIdx = m0 >> tcShift;
  const int tb = (m0 & ((1 << tcShift) - 1)) + t0;
  const unsigned short* Ag = A + ((size_t)bIdx * nT + tb + srow) * 256 + scol;
  const unsigned short* Wg = W + (size_t)(n0 + srow) * 256 + scol;
  unsigned short* AsW = As + wid * 512;
  unsigned short* BsW = Bs + wid * 512;

  f32x4 acc[4][4] = {};
  for (int kt = 0; kt < 8; kt++) {
    const int ko = kt * 32;
    GLDS(Ag + ko, AsW);
    GLDS(Ag + ko + 64 * 256, AsW + 2048);
    GLDS(Wg + ko, BsW);
    GLDS(Wg + ko + 64 * 256, BsW + 2048);
    __syncthreads();
    bf16x8 af[4], bfv[4];
    const int kr = (lane >> 4) * 8;
    const int rA = wrow * 64 + (lane & 15);
    const int rB = wcol * 64 + (lane & 15);
#pragma unroll
    for (int mi = 0; mi < 4; mi++) af[mi] = *(const bf16x8*)&As[(rA + mi * 16) * 32 + kr];
#pragma unroll
    for (int ni = 0; ni < 4; ni++) bfv[ni] = *(const bf16x8*)&Bs[(rB + ni * 16) * 32 + kr];
#pragma unroll
    for (int mi = 0; mi < 4; mi++)
#pragma unroll
      for (int ni = 0; ni < 4; ni++)
        acc[mi][ni] = __builtin_amdgcn_mfma_f32_16x16x32_bf16(af[mi], bfv[ni], acc[mi][ni], 0, 0, 0);
    __syncthreads();
  }
#pragma unroll
  for (int ni = 0; ni < 4; ni++) {
    const int col = n0 + wcol * 64 + ni * 16 + (lane & 15);
    const float bv = bih[col];
#pragma unroll
    for (int mi = 0; mi < 4; mi++) {
      const int row = m0 + wrow * 64 + mi * 16 + (lane >> 4) * 4;
#pragma unroll
      for (int r = 0; r < 4; r++)
        out[(size_t)(row + r) * 768 + col] = (_Float16)(acc[mi][ni][r] + bv);
    }
  }
}

// ---------------- GEMM: fused GLU  h += (s@g1w^T+g1b)*sigmoid(s@g2w^T+g2b) -------------
__global__ __launch_bounds__(256) void k_gemm_glu(const unsigned short* __restrict__ A,
                                                  const unsigned short* __restrict__ W1,
                                                  const unsigned short* __restrict__ W2,
                                                  const float* __restrict__ b1,
                                                  const float* __restrict__ b2,
                                                  float* __restrict__ h) {
  __shared__ __align__(16) unsigned short As[128 * 32];
  __shared__ __align__(16) unsigned short B1s[128 * 32];
  __shared__ __align__(16) unsigned short B2s[128 * 32];
  const int tid = threadIdx.x;
  const int lane = tid & 63, wid = tid >> 6;
  const int m0 = blockIdx.y * 128, n0 = blockIdx.x * 128;
  const int wrow = wid >> 1, wcol = wid & 1;
  const int srow = tid >> 2;
  const int scol = (tid & 3) * 8;
  const unsigned short* Ag = A + (size_t)(m0 + srow) * 256 + scol;
  const unsigned short* W1g = W1 + (size_t)(n0 + srow) * 256 + scol;
  const unsigned short* W2g = W2 + (size_t)(n0 + srow) * 256 + scol;
  unsigned short* AsW = As + wid * 512;
  unsigned short* B1sW = B1s + wid * 512;
  unsigned short* B2sW = B2s + wid * 512;

  f32x4 acc1[4][4] = {};
  f32x4 acc2[4][4] = {};
  for (int kt = 0; kt < 8; kt++) {
    const int ko = kt * 32;
    GLDS(Ag + ko, AsW);
    GLDS(Ag + ko + 64 * 256, AsW + 2048);
    GLDS(W1g + ko, B1sW);
    GLDS(W1g + ko + 64 * 256, B1sW + 2048);
    GLDS(W2g + ko, B2sW);
    GLDS(W2g + ko + 64 * 256, B2sW + 2048);
    __syncthreads();
    bf16x8 af[4], b1v[4], b2v[4];
    const int kr = (lane >> 4) * 8;
    const int rA = wrow * 64 + (lane & 15);
    const int rB = wcol * 64 + (lane & 15);
#pragma unroll
    for (int mi = 0; mi < 4; mi++) af[mi] = *(const bf16x8*)&As[(rA + mi * 16) * 32 + kr];
#pragma unroll
    for (int ni = 0; ni < 4; ni++) {
      b1v[ni] = *(const bf16x8*)&B1s[(rB + ni * 16) * 32 + kr];
      b2v[ni] = *(const bf16x8*)&B2s[(rB + ni * 16) * 32 + kr];
    }
#pragma unroll
    for (int mi = 0; mi < 4; mi++)
#pragma unroll
      for (int ni = 0; ni < 4; ni++) {
        acc1[mi][ni] = __builtin_amdgcn_mfma_f32_16x16x32_bf16(af[mi], b1v[ni], acc1[mi][ni], 0, 0, 0);
        acc2[mi][ni] = __builtin_amdgcn_mfma_f32_16x16x32_bf16(af[mi], b2v[ni], acc2[mi][ni], 0, 0, 0);
      }
    __syncthreads();
  }
#pragma unroll
  for (int ni = 0; ni < 4; ni++) {
    const int col = n0 + wcol * 64 + ni * 16 + (lane & 15);
    const float bv1 = b1[col];
    const float bv2 = b2[col];
#pragma unroll
    for (int mi = 0; mi < 4; mi++) {
      const int row = m0 + wrow * 64 + mi * 16 + (lane >> 4) * 4;
#pragma unroll
      for (int r = 0; r < 4; r++) {
        float v1 = acc1[mi][ni][r] + bv1;
        float v2 = acc2[mi][ni][r] + bv2;
        size_t o = (size_t)(row + r) * nH + col;
        h[o] = h[o] + v1 * sigm(v2);
      }
    }
  }
}

// ---------------- GRU scan (chunked): 64 blocks (1 batch row each), 1024 threads -------
// thread tid: j = tid>>2 (output index), p = tid&3 (k-quarter). 96 weight dwords/thread
// -> fits the 128-VGPR budget at __launch_bounds__(1024,4) with NO AGPR/scratch spill.
// h LDS quarters padded to 72 halfs so the 4 broadcast addresses hit distinct banks.
__global__ __launch_bounds__(1024, 4) void k_gru_scan(const unsigned int* __restrict__ wpk,
                                                      const _Float16* __restrict__ ig,
                                                      const float* __restrict__ bn,
                                                      unsigned short* __restrict__ s_out,
                                                      float* __restrict__ hstate,
                                                      int Tc, int t0, int first) {
  const int tid = threadIdx.x;
  const int b = blockIdx.x;
  const int j = tid >> 2, p = tid & 3;
  __shared__ __align__(16) _Float16 hlds[2][4][72];

  // 96 weight dwords -> arch VGPRs, loaded as 24 dwordx4
  unsigned int wr[32], wz[32], wn[32];
  {
    const uint4v* wp4 = (const uint4v*)(wpk + (size_t)tid * 96);
#pragma unroll
    for (int q = 0; q < 8; q++) {
      uint4v v0 = wp4[q], v1 = wp4[8 + q], v2 = wp4[16 + q];
#pragma unroll
      for (int d = 0; d < 4; d++) {
        wr[q * 4 + d] = v0[d];
        wz[q * 4 + d] = v1[d];
        wn[q * 4 + d] = v2[d];
      }
    }
  }
  const float bnj = bn[j];
  float hprev = first ? 0.f : hstate[b * 256 + j];
  if (p == 0) hlds[0][j >> 6][j & 63] = (_Float16)hprev;
  const _Float16* igrow = ig + (size_t)b * Tc * 768;
  _Float16 cR = igrow[j], cZ = igrow[256 + j], cN = igrow[512 + j];
  unsigned short* srow = s_out + ((size_t)b * nT + t0) * nS;
  __syncthreads();

  int cur = 0;
  for (int t = 0; t < Tc; t++) {
    // prefetch next timestep's input gates (overlaps the dot loop)
    _Float16 nR = cR, nZ = cZ, nN = cN;
    if (t + 1 < Tc) {
      const _Float16* nx = igrow + (size_t)(t + 1) * 768;
      nR = nx[j];
      nZ = nx[256 + j];
      nN = nx[512 + j];
    }
    // this thread's k-quarter: h[p*64 .. p*64+63], sequential per-gate accumulation
    float ar = 0.f, az = 0.f, an = 0.f;
    const half2v* h2 = (const half2v*)&hlds[cur][p][0];
#pragma unroll
    for (int q = 0; q < 32; q++) {
      half2v hp = h2[q];
      ar = fdot2_(__builtin_bit_cast(half2v, wr[q]), hp, ar);
      az = fdot2_(__builtin_bit_cast(half2v, wz[q]), hp, az);
      an = fdot2_(__builtin_bit_cast(half2v, wn[q]), hp, an);
    }
    // 4-lane group sum; all 4 lanes end with the full dot
    ar += __shfl_xor(ar, 1);
    ar += __shfl_xor(ar, 2);
    az += __shfl_xor(az, 1);
    az += __shfl_xor(az, 2);
    an += __shfl_xor(an, 1);
    an += __shfl_xor(an, 2);
    float r = sigm((float)cR + ar);
    float z = sigm((float)cZ + az);
    float n = tanh_f((float)cN + r * (an + bnj));
    float hnew = fmaf(z, hprev - n, n);  // (1-z)*n + z*h
    hprev = hnew;
    if (p == 0) {
      hlds[cur ^ 1][j >> 6][j & 63] = (_Float16)hnew;   // p==0: LDS state write
    } else if (p == 1) {
      srow[(size_t)t * nS + j] = f2bf(gelu_f(hnew));    // p==1: gelu + global store
    }
    __syncthreads();
    cur ^= 1;
    cR = nR;
    cZ = nZ;
    cN = nN;
  }
  if (p == 0) hstate[b * 256 + j] = hprev;
}

// ---------------- decoder: out = tanh(h @ dec_w^T + dec_b) ----------------
__global__ __launch_bounds__(256) void k_decoder(const float* __restrict__ h,
                                                 const float* __restrict__ dw,
                                                 const float* __restrict__ db,
                                                 float* __restrict__ out) {
  __shared__ float hs[8][256];
  __shared__ float ws[32][257];
  const int tid = threadIdx.x;
  for (int q = tid; q < 32 * 256; q += 256) ws[q >> 8][q & 255] = dw[q];
  const int r0 = blockIdx.x * 8;
  for (int q = tid; q < 8 * 256; q += 256)
    hs[q >> 8][q & 255] = h[(size_t)(r0 + (q >> 8)) * nH + (q & 255)];
  __syncthreads();
  const int r = tid >> 5, o = tid & 31;
  float acc = db[o];
#pragma unroll 8
  for (int k = 0; k < 256; k++) acc = fmaf(hs[r][k], ws[o][k], acc);
  out[(size_t)(r0 + r) * nOUT + o] = tanh_f(acc);
}

// ---------------- host ----------------
extern "C" void kernel_launch(void* const* d_in, const int* in_sizes, int n_in,
                              void* d_out, int out_size, void* d_ws, size_t ws_size,
                              hipStream_t stream) {
  const float* x = (const float*)d_in[0];
  const float* enc_w = (const float*)d_in[1];
  const float* enc_b = (const float*)d_in[2];
  const float* wih = (const float*)d_in[3];
  const float* whh = (const float*)d_in[4];
  const float* b_ih = (const float*)d_in[5];
  const float* b_n = (const float*)d_in[6];
  const float* g1w = (const float*)d_in[7];
  const float* g1b = (const float*)d_in[8];
  const float* g2w = (const float*)d_in[9];
  const float* g2b = (const float*)d_in[10];
  const float* dec_w = (const float*)d_in[11];
  const float* dec_b = (const float*)d_in[12];

  // ---- workspace layout (fixed part ~198 MiB; ig chunk sized to fit ws_size) ----
  char* w = (char*)d_ws;
  float* h = (float*)w;                        w += (size_t)nBT * nH * 4;      // 128 MiB
  unsigned short* hs = (unsigned short*)w;     w += (size_t)nBT * nH * 2;      // 64 MiB (hn, then s)
  float* psum = (float*)w;                     w += (size_t)256 * 1024 * 4;    // 1 MiB
  float* psq = (float*)w;                      w += (size_t)256 * 1024 * 4;    // 1 MiB
  float* mean = (float*)w;                     w += 1024;
  float* istd = (float*)w;                     w += 1024;
  float* hstate = (float*)w;                   w += (size_t)nB * nS * 4;       // 64 KiB
  unsigned short* wih_b = (unsigned short*)w;  w += (size_t)nNB * 768 * 256 * 2;
  unsigned short* g1w_b = (unsigned short*)w;  w += (size_t)nNB * 256 * 256 * 2;
  unsigned short* g2w_b = (unsigned short*)w;  w += (size_t)nNB * 256 * 256 * 2;
  unsigned int* whh_pk = (unsigned int*)w;     w += (size_t)nNB * 1024 * 96 * 4;
  _Float16* ig = (_Float16*)w;                 // chunk buffer, sized below
  size_t fixedBytes = (size_t)(w - (char*)d_ws);

  // choose the largest power-of-2 time-chunk whose ig buffer fits the workspace
  int tcShift = 11;  // Tc = 2048 (whole sequence)
  while (tcShift > 7 && fixedBytes + (((size_t)nB << tcShift) * 768 * 2) > ws_size) tcShift--;
  const int Tc = 1 << tcShift;
  const int nChunks = nT / Tc;

  // weight prep
  k_cvt_bf16<<<1024, 256, 0, stream>>>(wih, wih_b, nNB * 768 * 256);
  k_cvt_bf16<<<512, 256, 0, stream>>>(g1w, g1w_b, nNB * 256 * 256);
  k_cvt_bf16<<<512, 256, 0, stream>>>(g2w, g2w_b, nNB * 256 * 256);
  k_pack_whh<<<1536, 256, 0, stream>>>(whh, whh_pk);

  // encoder
  k_encoder<<<nBT / 32, 256, 0, stream>>>(x, enc_w, enc_b, h);

  for (int i = 0; i < nNB; i++) {
    k_bn_partial<<<1024, 256, 0, stream>>>(h, psum, psq);
    k_bn_final<<<256, 256, 0, stream>>>(psum, psq, mean, istd);
    k_norm_cvt<<<2048, 256, 0, stream>>>(h, mean, istd, hs);
    for (int c = 0; c < nChunks; c++) {
      k_gemm_ig<<<dim3(6, (nB * Tc) / 128), 256, 0, stream>>>(
          hs, wih_b + (size_t)i * 768 * 256, b_ih + i * 768, ig, c * Tc, tcShift);
      k_gru_scan<<<nB, 1024, 0, stream>>>(whh_pk + (size_t)i * 1024 * 96, ig, b_n + i * 256,
                                          hs, hstate, Tc, c * Tc, c == 0 ? 1 : 0);
    }
    k_gemm_glu<<<dim3(2, nBT / 128), 256, 0, stream>>>(hs, g1w_b + (size_t)i * 256 * 256,
                                                       g2w_b + (size_t)i * 256 * 256,
                                                       g1b + i * 256, g2b + i * 256, h);
  }

  k_decoder<<<nBT / 8, 256, 0, stream>>>(h, dec_w, dec_b, (float*)d_out);
}

// Round 9
// 10497.980 us; speedup vs baseline: 1.2000x; 1.2000x over previous
//
#include <hip/hip_runtime.h>
#include <hip/hip_bf16.h>
#include <hip/hip_fp16.h>

// Problem constants
constexpr int nB = 64, nT = 2048, nIN = 32, nH = 256, nS = 256, nOUT = 32, nNB = 4;
constexpr int nBT = nB * nT;  // 131072

typedef __attribute__((ext_vector_type(2))) _Float16 half2v;
typedef __attribute__((ext_vector_type(4))) float f32x4;
typedef __attribute__((ext_vector_type(8))) short bf16x8;
typedef __attribute__((ext_vector_type(4))) unsigned short us4;
typedef __attribute__((ext_vector_type(4))) unsigned int uint4v;

#define GLDS(gsrc, ldst)                                                        \
  __builtin_amdgcn_global_load_lds(                                             \
      (const __attribute__((address_space(1))) void*)(gsrc),                    \
      (__attribute__((address_space(3))) void*)(ldst), 16, 0, 0)

__device__ __forceinline__ float fast_exp(float x) {
  return __builtin_amdgcn_exp2f(x * 1.44269504088896f);
}
__device__ __forceinline__ float sigm(float x) {
  return __builtin_amdgcn_rcpf(1.f + fast_exp(-x));
}
__device__ __forceinline__ float tanh_f(float x) {
  float ax = fabsf(x);
  float e = fast_exp(-2.f * ax);
  float r = 1.f - 2.f * e * __builtin_amdgcn_rcpf(1.f + e);
  return copysignf(r, x);
}
__device__ __forceinline__ float gelu_f(float x) {
  float x3 = x * x * x;
  return 0.5f * x * (1.f + tanh_f(0.79788456080286536f * (x + 0.044715f * x3)));
}
__device__ __forceinline__ unsigned short f2bf(float f) {
  unsigned int u = __builtin_bit_cast(unsigned int, f);
  unsigned int r = (u + 0x7fffu + ((u >> 16) & 1u)) >> 16;
  return (unsigned short)r;
}
__device__ __forceinline__ float fdot2_(half2v a, half2v b, float c) {
#if __has_builtin(__builtin_amdgcn_fdot2)
  return __builtin_amdgcn_fdot2(a, b, c, false);
#else
  return fmaf((float)a.x, (float)b.x, fmaf((float)a.y, (float)b.y, c));
#endif
}

// ---------------- weight prep ----------------
__global__ __launch_bounds__(256) void k_cvt_bf16(const float* __restrict__ src,
                                                  unsigned short* __restrict__ dst, int n) {
  for (int i = blockIdx.x * 256 + threadIdx.x; i < n; i += gridDim.x * 256)
    dst[i] = f2bf(src[i]);
}

// whh (NB,768,256) f32 -> per-thread packed half2 (512-thread scan, 2-way k-split):
// idx = ((i*512 + t)*3 + g)*64 + kk ; t=(j<<1)|p ; k0 = p*128 + 2*kk
__global__ __launch_bounds__(256) void k_pack_whh(const float* __restrict__ whh,
                                                  unsigned int* __restrict__ dst) {
  int idx = blockIdx.x * 256 + threadIdx.x;
  int total = nNB * 512 * 3 * 64;
  if (idx >= total) return;
  int kk = idx & 63;
  int rest = idx >> 6;
  int g = rest % 3;
  int rest2 = rest / 3;
  int t = rest2 & 511;
  int i = rest2 >> 9;
  int j = t >> 1, p = t & 1;
  int k0 = p * 128 + kk * 2;
  const float* wrow = whh + ((size_t)i * 768 + g * 256 + j) * 256;
  unsigned short a = __builtin_bit_cast(unsigned short, (_Float16)wrow[k0]);
  unsigned short b = __builtin_bit_cast(unsigned short, (_Float16)wrow[k0 + 1]);
  dst[idx] = (unsigned int)a | ((unsigned int)b << 16);
}

// ---------------- encoder ----------------
__global__ __launch_bounds__(256) void k_encoder(const float* __restrict__ x,
                                                 const float* __restrict__ ew,
                                                 const float* __restrict__ eb,
                                                 float* __restrict__ h) {
  __shared__ float xs[32][32];
  int tid = threadIdx.x;
  int r0 = blockIdx.x * 32;
  for (int q = tid; q < 32 * 32; q += 256)
    xs[q >> 5][q & 31] = x[(size_t)(r0 + (q >> 5)) * nIN + (q & 31)];
  float w[32];
#pragma unroll
  for (int k = 0; k < 32; k++) w[k] = ew[tid * 32 + k];
  float b = eb[tid];
  __syncthreads();
  for (int r = 0; r < 32; r++) {
    float acc = b;
#pragma unroll
    for (int k = 0; k < 32; k++) acc = fmaf(xs[r][k], w[k], acc);
    h[(size_t)(r0 + r) * nH + tid] = acc;
  }
}

// ---------------- batchnorm stats ----------------
__global__ __launch_bounds__(256) void k_bn_partial(const float* __restrict__ h,
                                                    float* __restrict__ psum,
                                                    float* __restrict__ psq) {
  int c = threadIdx.x;
  int blk = blockIdx.x;  // 1024 blocks x 128 rows
  size_t base = (size_t)blk * 128 * nH + c;
  float s = 0.f, s2 = 0.f;
  for (int r = 0; r < 128; r++) {
    float v = h[base + (size_t)r * nH];
    s += v;
    s2 = fmaf(v, v, s2);
  }
  psum[c * 1024 + blk] = s;
  psq[c * 1024 + blk] = s2;
}

__global__ __launch_bounds__(256) void k_bn_final(const float* __restrict__ psum,
                                                  const float* __restrict__ psq,
                                                  float* __restrict__ mean,
                                                  float* __restrict__ istd) {
  int c = blockIdx.x;
  int t = threadIdx.x;
  __shared__ float rs[256], rq[256];
  float s = 0.f, q = 0.f;
#pragma unroll
  for (int p = 0; p < 4; p++) {
    s += psum[c * 1024 + t + 256 * p];
    q += psq[c * 1024 + t + 256 * p];
  }
  rs[t] = s;
  rq[t] = q;
  __syncthreads();
  for (int off = 128; off; off >>= 1) {
    if (t < off) {
      rs[t] += rs[t + off];
      rq[t] += rq[t + off];
    }
    __syncthreads();
  }
  if (t == 0) {
    float m = rs[0] * (1.f / (float)nBT);
    float v = rq[0] * (1.f / (float)nBT) - m * m;
    mean[c] = m;
    istd[c] = rsqrtf(v + 1e-5f);
  }
}

__global__ __launch_bounds__(256) void k_norm_cvt(const float* __restrict__ h,
                                                  const float* __restrict__ mean,
                                                  const float* __restrict__ istd,
                                                  unsigned short* __restrict__ hn) {
  __shared__ float ms[256], is[256];
  int t = threadIdx.x;
  ms[t] = mean[t];
  is[t] = istd[t];
  __syncthreads();
  size_t total = (size_t)nBT * (nH / 4);
  for (size_t idx = (size_t)blockIdx.x * 256 + t; idx < total; idx += (size_t)gridDim.x * 256) {
    f32x4 v = ((const f32x4*)h)[idx];
    int c0 = (int)((idx & 63) * 4);
    us4 o;
    o.x = f2bf((v.x - ms[c0 + 0]) * is[c0 + 0]);
    o.y = f2bf((v.y - ms[c0 + 1]) * is[c0 + 1]);
    o.z = f2bf((v.z - ms[c0 + 2]) * is[c0 + 2]);
    o.w = f2bf((v.w - ms[c0 + 3]) * is[c0 + 3]);
    ((us4*)hn)[idx] = o;
  }
}

// ---------------- GEMM: ig_chunk = hn_chunk @ wih^T + b_ih --------------------------
__global__ __launch_bounds__(256) void k_gemm_ig(const unsigned short* __restrict__ A,
                                                 const unsigned short* __restrict__ W,
                                                 const float* __restrict__ bih,
                                                 _Float16* __restrict__ out,
                                                 int t0, int tcShift) {
  __shared__ __align__(16) unsigned short As[128 * 32];
  __shared__ __align__(16) unsigned short Bs[128 * 32];
  const int tid = threadIdx.x;
  const int lane = tid & 63, wid = tid >> 6;
  const int m0 = blockIdx.y * 128, n0 = blockIdx.x * 128;
  const int wrow = wid >> 1, wcol = wid & 1;
  const int srow = tid >> 2;
  const int scol = (tid & 3) * 8;
  const int bIdx = m0 >> tcShift;
  const int tb = (m0 & ((1 << tcShift) - 1)) + t0;
  const unsigned short* Ag = A + ((size_t)bIdx * nT + tb + srow) * 256 + scol;
  const unsigned short* Wg = W + (size_t)(n0 + srow) * 256 + scol;
  unsigned short* AsW = As + wid * 512;
  unsigned short* BsW = Bs + wid * 512;

  f32x4 acc[4][4] = {};
  for (int kt = 0; kt < 8; kt++) {
    const int ko = kt * 32;
    GLDS(Ag + ko, AsW);
    GLDS(Ag + ko + 64 * 256, AsW + 2048);
    GLDS(Wg + ko, BsW);
    GLDS(Wg + ko + 64 * 256, BsW + 2048);
    __syncthreads();
    bf16x8 af[4], bfv[4];
    const int kr = (lane >> 4) * 8;
    const int rA = wrow * 64 + (lane & 15);
    const int rB = wcol * 64 + (lane & 15);
#pragma unroll
    for (int mi = 0; mi < 4; mi++) af[mi] = *(const bf16x8*)&As[(rA + mi * 16) * 32 + kr];
#pragma unroll
    for (int ni = 0; ni < 4; ni++) bfv[ni] = *(const bf16x8*)&Bs[(rB + ni * 16) * 32 + kr];
#pragma unroll
    for (int mi = 0; mi < 4; mi++)
#pragma unroll
      for (int ni = 0; ni < 4; ni++)
        acc[mi][ni] = __builtin_amdgcn_mfma_f32_16x16x32_bf16(af[mi], bfv[ni], acc[mi][ni], 0, 0, 0);
    __syncthreads();
  }
#pragma unroll
  for (int ni = 0; ni < 4; ni++) {
    const int col = n0 + wcol * 64 + ni * 16 + (lane & 15);
    const float bv = bih[col];
#pragma unroll
    for (int mi = 0; mi < 4; mi++) {
      const int row = m0 + wrow * 64 + mi * 16 + (lane >> 4) * 4;
#pragma unroll
      for (int r = 0; r < 4; r++)
        out[(size_t)(row + r) * 768 + col] = (_Float16)(acc[mi][ni][r] + bv);
    }
  }
}

// ---------------- GEMM: fused GLU  h += (s@g1w^T+g1b)*sigmoid(s@g2w^T+g2b) -------------
__global__ __launch_bounds__(256) void k_gemm_glu(const unsigned short* __restrict__ A,
                                                  const unsigned short* __restrict__ W1,
                                                  const unsigned short* __restrict__ W2,
                                                  const float* __restrict__ b1,
                                                  const float* __restrict__ b2,
                                                  float* __restrict__ h) {
  __shared__ __align__(16) unsigned short As[128 * 32];
  __shared__ __align__(16) unsigned short B1s[128 * 32];
  __shared__ __align__(16) unsigned short B2s[128 * 32];
  const int tid = threadIdx.x;
  const int lane = tid & 63, wid = tid >> 6;
  const int m0 = blockIdx.y * 128, n0 = blockIdx.x * 128;
  const int wrow = wid >> 1, wcol = wid & 1;
  const int srow = tid >> 2;
  const int scol = (tid & 3) * 8;
  const unsigned short* Ag = A + (size_t)(m0 + srow) * 256 + scol;
  const unsigned short* W1g = W1 + (size_t)(n0 + srow) * 256 + scol;
  const unsigned short* W2g = W2 + (size_t)(n0 + srow) * 256 + scol;
  unsigned short* AsW = As + wid * 512;
  unsigned short* B1sW = B1s + wid * 512;
  unsigned short* B2sW = B2s + wid * 512;

  f32x4 acc1[4][4] = {};
  f32x4 acc2[4][4] = {};
  for (int kt = 0; kt < 8; kt++) {
    const int ko = kt * 32;
    GLDS(Ag + ko, AsW);
    GLDS(Ag + ko + 64 * 256, AsW + 2048);
    GLDS(W1g + ko, B1sW);
    GLDS(W1g + ko + 64 * 256, B1sW + 2048);
    GLDS(W2g + ko, B2sW);
    GLDS(W2g + ko + 64 * 256, B2sW + 2048);
    __syncthreads();
    bf16x8 af[4], b1v[4], b2v[4];
    const int kr = (lane >> 4) * 8;
    const int rA = wrow * 64 + (lane & 15);
    const int rB = wcol * 64 + (lane & 15);
#pragma unroll
    for (int mi = 0; mi < 4; mi++) af[mi] = *(const bf16x8*)&As[(rA + mi * 16) * 32 + kr];
#pragma unroll
    for (int ni = 0; ni < 4; ni++) {
      b1v[ni] = *(const bf16x8*)&B1s[(rB + ni * 16) * 32 + kr];
      b2v[ni] = *(const bf16x8*)&B2s[(rB + ni * 16) * 32 + kr];
    }
#pragma unroll
    for (int mi = 0; mi < 4; mi++)
#pragma unroll
      for (int ni = 0; ni < 4; ni++) {
        acc1[mi][ni] = __builtin_amdgcn_mfma_f32_16x16x32_bf16(af[mi], b1v[ni], acc1[mi][ni], 0, 0, 0);
        acc2[mi][ni] = __builtin_amdgcn_mfma_f32_16x16x32_bf16(af[mi], b2v[ni], acc2[mi][ni], 0, 0, 0);
      }
    __syncthreads();
  }
#pragma unroll
  for (int ni = 0; ni < 4; ni++) {
    const int col = n0 + wcol * 64 + ni * 16 + (lane & 15);
    const float bv1 = b1[col];
    const float bv2 = b2[col];
#pragma unroll
    for (int mi = 0; mi < 4; mi++) {
      const int row = m0 + wrow * 64 + mi * 16 + (lane >> 4) * 4;
#pragma unroll
      for (int r = 0; r < 4; r++) {
        float v1 = acc1[mi][ni][r] + bv1;
        float v2 = acc2[mi][ni][r] + bv2;
        size_t o = (size_t)(row + r) * nH + col;
        h[o] = h[o] + v1 * sigm(v2);
      }
    }
  }
}

// ---------------- GRU scan (chunked): 64 blocks (1 batch row each), 512 threads --------
// ROUND-4 kernel verbatim (known PASS) + an 80 KiB LDS occupancy pad: total LDS/block
// ~81 KiB -> 2 blocks/CU physically impossible (162 > 160 KiB) -> 64 blocks spread
// across 64 CUs. Pure scheduling change; numerics bit-identical to round 4.
__global__ __launch_bounds__(512, 2) void k_gru_scan(const unsigned int* __restrict__ wpk,
                                                     const _Float16* __restrict__ ig,
                                                     const float* __restrict__ bn,
                                                     unsigned short* __restrict__ s_out,
                                                     float* __restrict__ hstate,
                                                     int Tc, int t0, int first) {
  const int tid = threadIdx.x;
  const int b = blockIdx.x;
  const int j = tid >> 1, p = tid & 1;
  __shared__ __align__(16) _Float16 hlds[2][256];
  __shared__ char occ_pad[80 * 1024];  // occupancy limiter: forces 1 block/CU
  if (tid == 0) occ_pad[0] = (char)first;  // ds_write keeps the allocation (no DCE)

  // 192 weight dwords (half2 pairs), loaded as 48 dwordx4 (round-4 form)
  unsigned int wr[64], wz[64], wn[64];
  {
    const uint4v* wp4 = (const uint4v*)(wpk + (size_t)tid * 192);
#pragma unroll
    for (int q = 0; q < 16; q++) {
      uint4v v0 = wp4[q], v1 = wp4[16 + q], v2 = wp4[32 + q];
#pragma unroll
      for (int d = 0; d < 4; d++) {
        wr[q * 4 + d] = v0[d];
        wz[q * 4 + d] = v1[d];
        wn[q * 4 + d] = v2[d];
      }
    }
  }
  const float bnj = bn[j];
  float hprev = first ? 0.f : hstate[b * 256 + j];
  if (p == 0) hlds[0][j] = (_Float16)hprev;
  const _Float16* igrow = ig + (size_t)b * Tc * 768;
  _Float16 cR = igrow[j], cZ = igrow[256 + j], cN = igrow[512 + j];
  unsigned short* srow = s_out + ((size_t)b * nT + t0) * nS;
  __syncthreads();

  int cur = 0;
  for (int t = 0; t < Tc; t++) {
    // prefetch next timestep's input gates (overlaps the dot loop)
    _Float16 nR = cR, nZ = cZ, nN = cN;
    if (t + 1 < Tc) {
      const _Float16* nx = igrow + (size_t)(t + 1) * 768;
      nR = nx[j];
      nZ = nx[256 + j];
      nN = nx[512 + j];
    }
    float ar = 0.f, az = 0.f, an = 0.f;
    const half2v* h2 = (const half2v*)hlds[cur];
#pragma unroll
    for (int q = 0; q < 64; q++) {
      half2v hp = h2[(p << 6) + q];
      ar = fdot2_(__builtin_bit_cast(half2v, wr[q]), hp, ar);
      az = fdot2_(__builtin_bit_cast(half2v, wz[q]), hp, az);
      an = fdot2_(__builtin_bit_cast(half2v, wn[q]), hp, an);
    }
    ar += __shfl_xor(ar, 1);
    az += __shfl_xor(az, 1);
    an += __shfl_xor(an, 1);
    float r = sigm((float)cR + ar);
    float z = sigm((float)cZ + az);
    float n = tanh_f((float)cN + r * (an + bnj));
    float hnew = fmaf(z, hprev - n, n);  // (1-z)*n + z*h
    hprev = hnew;
    if (p == 0) {
      hlds[cur ^ 1][j] = (_Float16)hnew;
      srow[(size_t)t * nS + j] = f2bf(gelu_f(hnew));
    }
    __syncthreads();
    cur ^= 1;
    cR = nR;
    cZ = nZ;
    cN = nN;
  }
  if (p == 0) hstate[b * 256 + j] = hprev;
}

// ---------------- decoder: out = tanh(h @ dec_w^T + dec_b) ----------------
__global__ __launch_bounds__(256) void k_decoder(const float* __restrict__ h,
                                                 const float* __restrict__ dw,
                                                 const float* __restrict__ db,
                                                 float* __restrict__ out) {
  __shared__ float hs[8][256];
  __shared__ float ws[32][257];
  const int tid = threadIdx.x;
  for (int q = tid; q < 32 * 256; q += 256) ws[q >> 8][q & 255] = dw[q];
  const int r0 = blockIdx.x * 8;
  for (int q = tid; q < 8 * 256; q += 256)
    hs[q >> 8][q & 255] = h[(size_t)(r0 + (q >> 8)) * nH + (q & 255)];
  __syncthreads();
  const int r = tid >> 5, o = tid & 31;
  float acc = db[o];
#pragma unroll 8
  for (int k = 0; k < 256; k++) acc = fmaf(hs[r][k], ws[o][k], acc);
  out[(size_t)(r0 + r) * nOUT + o] = tanh_f(acc);
}

// ---------------- host ----------------
extern "C" void kernel_launch(void* const* d_in, const int* in_sizes, int n_in,
                              void* d_out, int out_size, void* d_ws, size_t ws_size,
                              hipStream_t stream) {
  const float* x = (const float*)d_in[0];
  const float* enc_w = (const float*)d_in[1];
  const float* enc_b = (const float*)d_in[2];
  const float* wih = (const float*)d_in[3];
  const float* whh = (const float*)d_in[4];
  const float* b_ih = (const float*)d_in[5];
  const float* b_n = (const float*)d_in[6];
  const float* g1w = (const float*)d_in[7];
  const float* g1b = (const float*)d_in[8];
  const float* g2w = (const float*)d_in[9];
  const float* g2b = (const float*)d_in[10];
  const float* dec_w = (const float*)d_in[11];
  const float* dec_b = (const float*)d_in[12];

  // ---- workspace layout (fixed part ~198 MiB; ig chunk sized to fit ws_size) ----
  char* w = (char*)d_ws;
  float* h = (float*)w;                        w += (size_t)nBT * nH * 4;      // 128 MiB
  unsigned short* hs = (unsigned short*)w;     w += (size_t)nBT * nH * 2;      // 64 MiB (hn, then s)
  float* psum = (float*)w;                     w += (size_t)256 * 1024 * 4;    // 1 MiB
  float* psq = (float*)w;                      w += (size_t)256 * 1024 * 4;    // 1 MiB
  float* mean = (float*)w;                     w += 1024;
  float* istd = (float*)w;                     w += 1024;
  float* hstate = (float*)w;                   w += (size_t)nB * nS * 4;       // 64 KiB
  unsigned short* wih_b = (unsigned short*)w;  w += (size_t)nNB * 768 * 256 * 2;
  unsigned short* g1w_b = (unsigned short*)w;  w += (size_t)nNB * 256 * 256 * 2;
  unsigned short* g2w_b = (unsigned short*)w;  w += (size_t)nNB * 256 * 256 * 2;
  unsigned int* whh_pk = (unsigned int*)w;     w += (size_t)nNB * 512 * 192 * 4;
  _Float16* ig = (_Float16*)w;                 // chunk buffer, sized below
  size_t fixedBytes = (size_t)(w - (char*)d_ws);

  // choose the largest power-of-2 time-chunk whose ig buffer fits the workspace
  int tcShift = 11;  // Tc = 2048 (whole sequence)
  while (tcShift > 7 && fixedBytes + (((size_t)nB << tcShift) * 768 * 2) > ws_size) tcShift--;
  const int Tc = 1 << tcShift;
  const int nChunks = nT / Tc;

  // weight prep
  k_cvt_bf16<<<1024, 256, 0, stream>>>(wih, wih_b, nNB * 768 * 256);
  k_cvt_bf16<<<512, 256, 0, stream>>>(g1w, g1w_b, nNB * 256 * 256);
  k_cvt_bf16<<<512, 256, 0, stream>>>(g2w, g2w_b, nNB * 256 * 256);
  k_pack_whh<<<1536, 256, 0, stream>>>(whh, whh_pk);

  // encoder
  k_encoder<<<nBT / 32, 256, 0, stream>>>(x, enc_w, enc_b, h);

  for (int i = 0; i < nNB; i++) {
    k_bn_partial<<<1024, 256, 0, stream>>>(h, psum, psq);
    k_bn_final<<<256, 256, 0, stream>>>(psum, psq, mean, istd);
    k_norm_cvt<<<2048, 256, 0, stream>>>(h, mean, istd, hs);
    for (int c = 0; c < nChunks; c++) {
      k_gemm_ig<<<dim3(6, (nB * Tc) / 128), 256, 0, stream>>>(
          hs, wih_b + (size_t)i * 768 * 256, b_ih + i * 768, ig, c * Tc, tcShift);
      k_gru_scan<<<nB, 512, 0, stream>>>(whh_pk + (size_t)i * 512 * 192, ig, b_n + i * 256,
                                         hs, hstate, Tc, c * Tc, c == 0 ? 1 : 0);
    }
    k_gemm_glu<<<dim3(2, nBT / 128), 256, 0, stream>>>(hs, g1w_b + (size_t)i * 256 * 256,
                                                       g2w_b + (size_t)i * 256 * 256,
                                                       g1b + i * 256, g2b + i * 256, h);
  }

  k_decoder<<<nBT / 8, 256, 0, stream>>>(h, dec_w, dec_b, (float*)d_out);
}